// Round 1
// baseline (162.716 us; speedup 1.0000x reference)
//
#include <hip/hip_runtime.h>
#include <hip/hip_bf16.h>
#include <cstdint>
#include <cstddef>

typedef __attribute__((ext_vector_type(8))) __bf16 bf16x8;
typedef __attribute__((ext_vector_type(4))) __bf16 bf16x4;
typedef __attribute__((ext_vector_type(4))) float f32x4;

#define BATCH 4096
#define IN_FEAT 1024
#define OUT_FEAT 1024
#define RNK 16
#define SCALE 2.0f

// ---------------- kernel 1: a = x @ A^T ; x_bf = bf16(x) ----------------
__global__ __launch_bounds__(256) void prep_x_kernel(
    const float* __restrict__ x, const float* __restrict__ A,
    float* __restrict__ a_out, __bf16* __restrict__ x_bf)
{
    __shared__ float xs[IN_FEAT];
    const int b = blockIdx.x;
    const int t = threadIdx.x;

    const float4 v = *reinterpret_cast<const float4*>(&x[(size_t)b * IN_FEAT + t * 4]);
    xs[t * 4 + 0] = v.x; xs[t * 4 + 1] = v.y;
    xs[t * 4 + 2] = v.z; xs[t * 4 + 3] = v.w;
    bf16x4 h;
    h[0] = (__bf16)v.x; h[1] = (__bf16)v.y; h[2] = (__bf16)v.z; h[3] = (__bf16)v.w;
    *reinterpret_cast<bf16x4*>(&x_bf[(size_t)b * IN_FEAT + t * 4]) = h;
    __syncthreads();

    const int r = t >> 4;      // 0..15 (rank index)
    const int l16 = t & 15;
    const float* __restrict__ Ar = &A[r * IN_FEAT];
    float s = 0.f;
    #pragma unroll 8
    for (int j = 0; j < IN_FEAT / 16; ++j) {
        const int k = l16 + 16 * j;
        s += xs[k] * Ar[k];
    }
    s += __shfl_xor(s, 8);
    s += __shfl_xor(s, 4);
    s += __shfl_xor(s, 2);
    s += __shfl_xor(s, 1);
    if (l16 == 0) a_out[b * RNK + r] = s;
}

// ---------------- kernel 2: W_base -> bf16 ----------------
__global__ __launch_bounds__(256) void conv_w_kernel(
    const float* __restrict__ W, __bf16* __restrict__ w_bf)
{
    const int idx = (blockIdx.x * 256 + threadIdx.x) * 4;
    const float4 v = *reinterpret_cast<const float4*>(&W[idx]);
    bf16x4 h;
    h[0] = (__bf16)v.x; h[1] = (__bf16)v.y; h[2] = (__bf16)v.z; h[3] = (__bf16)v.w;
    *reinterpret_cast<bf16x4*>(&w_bf[idx]) = h;
}

// ---------------- kernel 3: fused base GEMM (MFMA) + LoRA gather epilogue ----
#define BM 64
#define BN 64
#define BK 64
#define LDK 72   // +8 bf16 pad: breaks the 128B-stride bank conflict

__global__ __launch_bounds__(256) void fused_kernel(
    const __bf16* __restrict__ x_bf, const __bf16* __restrict__ w_bf,
    const float* __restrict__ a_buf,
    const int* __restrict__ uidx, const int* __restrict__ iidx,
    const float* __restrict__ b_base,
    const float* __restrict__ B_user, const float* __restrict__ B_item,
    const float* __restrict__ W_common,
    float* __restrict__ out)
{
    __shared__ __align__(16) __bf16 xs[BM * LDK];
    __shared__ __align__(16) __bf16 wsh[BN * LDK];
    __shared__ __align__(16) float a_s[BM * RNK];
    __shared__ int u_s[BM];
    __shared__ int i_s[BM];

    const int t = threadIdx.x;
    const int o0 = blockIdx.x * BN;
    const int b0 = blockIdx.y * BM;

    if (t < BM) {
        u_s[t] = uidx[b0 + t];
        i_s[t] = iidx[b0 + t];
    }
    // 64 rows x 16 ranks = 1024 floats, 4 per thread
    *reinterpret_cast<float4*>(&a_s[t * 4]) =
        *reinterpret_cast<const float4*>(&a_buf[(size_t)b0 * RNK + t * 4]);

    const int w  = t >> 6;          // wave 0..3
    const int wr = w >> 1;          // wave row (2)
    const int wc = w & 1;           // wave col (2)
    const int l  = t & 63;
    const int lr = l & 15;
    const int lg = l >> 4;

    const int srow  = t >> 2;         // staging row 0..63
    const int skoff = (t & 3) * 16;   // staging elem offset (32B per thread)

    f32x4 acc[2][2] = {};

    for (int kt = 0; kt < IN_FEAT; kt += BK) {
        __syncthreads();
        {
            const uint4* g = reinterpret_cast<const uint4*>(
                &x_bf[(size_t)(b0 + srow) * IN_FEAT + kt + skoff]);
            uint4 v0 = g[0], v1 = g[1];
            *reinterpret_cast<uint4*>(&xs[srow * LDK + skoff]) = v0;
            *reinterpret_cast<uint4*>(&xs[srow * LDK + skoff + 8]) = v1;
            const uint4* gw = reinterpret_cast<const uint4*>(
                &w_bf[(size_t)(o0 + srow) * IN_FEAT + kt + skoff]);
            uint4 w0 = gw[0], w1 = gw[1];
            *reinterpret_cast<uint4*>(&wsh[srow * LDK + skoff]) = w0;
            *reinterpret_cast<uint4*>(&wsh[srow * LDK + skoff + 8]) = w1;
        }
        __syncthreads();

        #pragma unroll
        for (int kk = 0; kk < BK; kk += 32) {
            bf16x8 af0 = *reinterpret_cast<const bf16x8*>(&xs[(wr * 32 + 0 * 16 + lr) * LDK + kk + lg * 8]);
            bf16x8 af1 = *reinterpret_cast<const bf16x8*>(&xs[(wr * 32 + 1 * 16 + lr) * LDK + kk + lg * 8]);
            bf16x8 bf0 = *reinterpret_cast<const bf16x8*>(&wsh[(wc * 32 + 0 * 16 + lr) * LDK + kk + lg * 8]);
            bf16x8 bf1 = *reinterpret_cast<const bf16x8*>(&wsh[(wc * 32 + 1 * 16 + lr) * LDK + kk + lg * 8]);
            acc[0][0] = __builtin_amdgcn_mfma_f32_16x16x32_bf16(af0, bf0, acc[0][0], 0, 0, 0);
            acc[0][1] = __builtin_amdgcn_mfma_f32_16x16x32_bf16(af0, bf1, acc[0][1], 0, 0, 0);
            acc[1][0] = __builtin_amdgcn_mfma_f32_16x16x32_bf16(af1, bf0, acc[1][0], 0, 0, 0);
            acc[1][1] = __builtin_amdgcn_mfma_f32_16x16x32_bf16(af1, bf1, acc[1][1], 0, 0, 0);
        }
    }

    // ---------- epilogue: bias + SCALE*( (Bu+Bi+Wc) · a ) ----------
    #pragma unroll
    for (int n = 0; n < 2; ++n) {
        const int o = o0 + wc * 32 + n * 16 + lr;
        const float bb = b_base[o];
        const float4* wcm = reinterpret_cast<const float4*>(&W_common[(size_t)o * RNK]);
        float4 cw0 = wcm[0], cw1 = wcm[1], cw2 = wcm[2], cw3 = wcm[3];
        #pragma unroll
        for (int m = 0; m < 2; ++m) {
            #pragma unroll
            for (int i = 0; i < 4; ++i) {
                const int bl = wr * 32 + m * 16 + lg * 4 + i;   // local batch row
                const size_t u  = (size_t)u_s[bl];
                const size_t ii = (size_t)i_s[bl];
                const float4* bu = reinterpret_cast<const float4*>(
                    &B_user[(u * OUT_FEAT + (size_t)o) * RNK]);
                const float4* bi = reinterpret_cast<const float4*>(
                    &B_item[(ii * OUT_FEAT + (size_t)o) * RNK]);
                const float4* av = reinterpret_cast<const float4*>(&a_s[bl * RNK]);

                float lora = 0.f;
                float4 cu, ci, aa;
                cu = bu[0]; ci = bi[0]; aa = av[0];
                lora += (cu.x + ci.x + cw0.x) * aa.x + (cu.y + ci.y + cw0.y) * aa.y
                      + (cu.z + ci.z + cw0.z) * aa.z + (cu.w + ci.w + cw0.w) * aa.w;
                cu = bu[1]; ci = bi[1]; aa = av[1];
                lora += (cu.x + ci.x + cw1.x) * aa.x + (cu.y + ci.y + cw1.y) * aa.y
                      + (cu.z + ci.z + cw1.z) * aa.z + (cu.w + ci.w + cw1.w) * aa.w;
                cu = bu[2]; ci = bi[2]; aa = av[2];
                lora += (cu.x + ci.x + cw2.x) * aa.x + (cu.y + ci.y + cw2.y) * aa.y
                      + (cu.z + ci.z + cw2.z) * aa.z + (cu.w + ci.w + cw2.w) * aa.w;
                cu = bu[3]; ci = bi[3]; aa = av[3];
                lora += (cu.x + ci.x + cw3.x) * aa.x + (cu.y + ci.y + cw3.y) * aa.y
                      + (cu.z + ci.z + cw3.z) * aa.z + (cu.w + ci.w + cw3.w) * aa.w;

                out[(size_t)(b0 + bl) * OUT_FEAT + o] = acc[m][n][i] + bb + SCALE * lora;
            }
        }
    }
}

extern "C" void kernel_launch(void* const* d_in, const int* in_sizes, int n_in,
                              void* d_out, int out_size, void* d_ws, size_t ws_size,
                              hipStream_t stream) {
    const float* x        = (const float*)d_in[0];
    const int*   uidx     = (const int*)d_in[1];
    const int*   iidx     = (const int*)d_in[2];
    const float* W_base   = (const float*)d_in[3];
    const float* b_base   = (const float*)d_in[4];
    const float* A        = (const float*)d_in[5];
    const float* B_user   = (const float*)d_in[6];
    const float* B_item   = (const float*)d_in[7];
    const float* W_common = (const float*)d_in[8];
    float* out = (float*)d_out;

    // workspace layout
    float*  a_buf = (float*)d_ws;                                   // 256 KB
    __bf16* x_bf  = (__bf16*)((char*)d_ws + (256 << 10));           // 8 MB
    __bf16* w_bf  = (__bf16*)((char*)d_ws + (256 << 10) + (8 << 20)); // 2 MB

    prep_x_kernel<<<BATCH, 256, 0, stream>>>(x, A, a_buf, x_bf);
    conv_w_kernel<<<(OUT_FEAT * IN_FEAT) / (256 * 4), 256, 0, stream>>>(W_base, w_bf);

    dim3 grid(OUT_FEAT / BN, BATCH / BM);
    fused_kernel<<<grid, 256, 0, stream>>>(x_bf, w_bf, a_buf, uidx, iidx,
                                           b_base, B_user, B_item, W_common, out);
}

// Round 2
// 132.563 us; speedup vs baseline: 1.2275x; 1.2275x over previous
//
#include <hip/hip_runtime.h>
#include <hip/hip_bf16.h>
#include <cstdint>
#include <cstddef>

typedef __attribute__((ext_vector_type(8))) __bf16 bf16x8;
typedef __attribute__((ext_vector_type(4))) __bf16 bf16x4;
typedef __attribute__((ext_vector_type(4))) float f32x4;

#define BATCH 4096
#define IN_FEAT 1024
#define OUT_FEAT 1024
#define RNK 16
#define SCALE 2.0f

// ---------------- kernel 1: a = x @ A^T ; x_bf = bf16(x); w_bf = bf16(W) ----
__global__ __launch_bounds__(256) void prep_kernel(
    const float* __restrict__ x, const float* __restrict__ A,
    const float* __restrict__ W,
    float* __restrict__ a_out, __bf16* __restrict__ x_bf,
    __bf16* __restrict__ w_bf)
{
    __shared__ float xs[IN_FEAT];
    const int b = blockIdx.x;
    const int t = threadIdx.x;

    // fold W_base->bf16 conversion into the first 1024 blocks (1 row each)
    if (b < OUT_FEAT) {
        const float4 wv = *reinterpret_cast<const float4*>(&W[(size_t)b * IN_FEAT + t * 4]);
        bf16x4 hw;
        hw[0] = (__bf16)wv.x; hw[1] = (__bf16)wv.y;
        hw[2] = (__bf16)wv.z; hw[3] = (__bf16)wv.w;
        *reinterpret_cast<bf16x4*>(&w_bf[(size_t)b * IN_FEAT + t * 4]) = hw;
    }

    const float4 v = *reinterpret_cast<const float4*>(&x[(size_t)b * IN_FEAT + t * 4]);
    xs[t * 4 + 0] = v.x; xs[t * 4 + 1] = v.y;
    xs[t * 4 + 2] = v.z; xs[t * 4 + 3] = v.w;
    bf16x4 h;
    h[0] = (__bf16)v.x; h[1] = (__bf16)v.y; h[2] = (__bf16)v.z; h[3] = (__bf16)v.w;
    *reinterpret_cast<bf16x4*>(&x_bf[(size_t)b * IN_FEAT + t * 4]) = h;
    __syncthreads();

    const int r = t >> 4;      // 0..15 (rank index)
    const int l16 = t & 15;
    const float* __restrict__ Ar = &A[r * IN_FEAT];
    float s = 0.f;
    #pragma unroll 8
    for (int j = 0; j < IN_FEAT / 16; ++j) {
        const int k = l16 + 16 * j;
        s += xs[k] * Ar[k];
    }
    s += __shfl_xor(s, 8);
    s += __shfl_xor(s, 4);
    s += __shfl_xor(s, 2);
    s += __shfl_xor(s, 1);
    if (l16 == 0) a_out[b * RNK + r] = s;
}

// ---------------- kernel 2: fused base GEMM (MFMA) + interleaved LoRA gather
#define BM 64
#define BN 64
#define BK 64
#define LDK 72   // +8 bf16 pad: breaks the 128B-stride bank conflict
#define CWS 20   // W_common LDS row stride (floats): spreads banks, 16B-aligned

__global__ __launch_bounds__(256) void fused_kernel(
    const __bf16* __restrict__ x_bf, const __bf16* __restrict__ w_bf,
    const float* __restrict__ a_buf,
    const int* __restrict__ uidx, const int* __restrict__ iidx,
    const float* __restrict__ b_base,
    const float* __restrict__ B_user, const float* __restrict__ B_item,
    const float* __restrict__ W_common,
    float* __restrict__ out)
{
    __shared__ __align__(16) __bf16 xs[BM * LDK];
    __shared__ __align__(16) __bf16 wsh[BN * LDK];
    __shared__ __align__(16) float a_s[BM * RNK];
    __shared__ __align__(16) float cw_s[BN * CWS];
    __shared__ float b_s[BN];
    __shared__ int u_s[BM];
    __shared__ int i_s[BM];

    const int t = threadIdx.x;

    // XCD-aware bijective swizzle: 1024 blocks, 8 XCDs, 128 contiguous per XCD.
    // Each XCD then owns 8 full batch panels (all 16 o-tiles) -> x fetched once,
    // W panel stays L2-resident.
    const int bid = blockIdx.y * gridDim.x + blockIdx.x;   // 0..1023
    const int nid = (bid & 7) * 128 + (bid >> 3);
    const int o0 = (nid & 15) * BN;
    const int b0 = (nid >> 4) * BM;

    if (t < BM) {
        u_s[t] = uidx[b0 + t];
        i_s[t] = iidx[b0 + t];
    }
    if (t < BN) b_s[t] = b_base[o0 + t];
    // 64 rows x 16 ranks = 1024 floats, 4 per thread
    *reinterpret_cast<float4*>(&a_s[t * 4]) =
        *reinterpret_cast<const float4*>(&a_buf[(size_t)b0 * RNK + t * 4]);
    {   // stage W_common panel [64][16] -> LDS stride CWS
        const int row = t >> 2, col = (t & 3) * 4;
        const float4 v = *reinterpret_cast<const float4*>(
            &W_common[(size_t)(o0 + row) * RNK + col]);
        *reinterpret_cast<float4*>(&cw_s[row * CWS + col]) = v;
    }

    const int w  = t >> 6;          // wave 0..3
    const int wr = w >> 1;          // wave row (2)
    const int wc = w & 1;           // wave col (2)
    const int l  = t & 63;
    const int lr = l & 15;
    const int lg = l >> 4;

    const int srow  = t >> 2;         // staging row 0..63
    const int skoff = (t & 3) * 16;   // staging elem offset (32B per thread)

    f32x4 acc[2][2] = {};

    #pragma unroll
    for (int kt = 0; kt < IN_FEAT / BK; ++kt) {   // 16 iterations, fully unrolled
        __syncthreads();
        // ---- stage next K-tile of x and W into LDS ----
        {
            const uint4* g = reinterpret_cast<const uint4*>(
                &x_bf[(size_t)(b0 + srow) * IN_FEAT + kt * BK + skoff]);
            uint4 v0 = g[0], v1 = g[1];
            *reinterpret_cast<uint4*>(&xs[srow * LDK + skoff]) = v0;
            *reinterpret_cast<uint4*>(&xs[srow * LDK + skoff + 8]) = v1;
            const uint4* gw = reinterpret_cast<const uint4*>(
                &w_bf[(size_t)(o0 + srow) * IN_FEAT + kt * BK + skoff]);
            uint4 w0 = gw[0], w1 = gw[1];
            *reinterpret_cast<uint4*>(&wsh[srow * LDK + skoff]) = w0;
            *reinterpret_cast<uint4*>(&wsh[srow * LDK + skoff + 8]) = w1;
        }

        // ---- one LoRA gather slot per K-iteration (static indices after unroll)
        {
            const int nn = kt >> 3;          // 0..1
            const int mm = (kt >> 2) & 1;    // 0..1
            const int ii = kt & 3;           // 0..3
            const int ol = wc * 32 + nn * 16 + lr;              // local out col
            const int o  = o0 + ol;
            const int bl = wr * 32 + mm * 16 + lg * 4 + ii;     // local batch row
            const size_t u  = (size_t)u_s[bl];
            const size_t iv = (size_t)i_s[bl];
            const float4* bu = reinterpret_cast<const float4*>(
                &B_user[(u * OUT_FEAT + (size_t)o) * RNK]);
            const float4* bi = reinterpret_cast<const float4*>(
                &B_item[(iv * OUT_FEAT + (size_t)o) * RNK]);
            const float4* av4 = reinterpret_cast<const float4*>(&a_s[bl * RNK]);
            const float4* cw4 = reinterpret_cast<const float4*>(&cw_s[ol * CWS]);
            float lora = 0.f;
            #pragma unroll
            for (int q = 0; q < 4; ++q) {
                const float4 cu = bu[q], ci = bi[q], aa = av4[q], cw = cw4[q];
                lora += (cu.x + ci.x + cw.x) * aa.x + (cu.y + ci.y + cw.y) * aa.y
                      + (cu.z + ci.z + cw.z) * aa.z + (cu.w + ci.w + cw.w) * aa.w;
            }
            acc[mm][nn][ii] += b_s[ol] + SCALE * lora;
        }
        __syncthreads();

        // ---- MFMA on the staged K-tile ----
        #pragma unroll
        for (int kk = 0; kk < BK; kk += 32) {
            bf16x8 af0 = *reinterpret_cast<const bf16x8*>(&xs[(wr * 32 + 0 * 16 + lr) * LDK + kk + lg * 8]);
            bf16x8 af1 = *reinterpret_cast<const bf16x8*>(&xs[(wr * 32 + 1 * 16 + lr) * LDK + kk + lg * 8]);
            bf16x8 bf0 = *reinterpret_cast<const bf16x8*>(&wsh[(wc * 32 + 0 * 16 + lr) * LDK + kk + lg * 8]);
            bf16x8 bf1 = *reinterpret_cast<const bf16x8*>(&wsh[(wc * 32 + 1 * 16 + lr) * LDK + kk + lg * 8]);
            acc[0][0] = __builtin_amdgcn_mfma_f32_16x16x32_bf16(af0, bf0, acc[0][0], 0, 0, 0);
            acc[0][1] = __builtin_amdgcn_mfma_f32_16x16x32_bf16(af0, bf1, acc[0][1], 0, 0, 0);
            acc[1][0] = __builtin_amdgcn_mfma_f32_16x16x32_bf16(af1, bf0, acc[1][0], 0, 0, 0);
            acc[1][1] = __builtin_amdgcn_mfma_f32_16x16x32_bf16(af1, bf1, acc[1][1], 0, 0, 0);
        }
    }

    // ---------- write-out: acc already holds base + bias + SCALE*lora ----------
    #pragma unroll
    for (int n = 0; n < 2; ++n) {
        const int o = o0 + wc * 32 + n * 16 + lr;
        #pragma unroll
        for (int m = 0; m < 2; ++m) {
            #pragma unroll
            for (int i = 0; i < 4; ++i) {
                const int bl = wr * 32 + m * 16 + lg * 4 + i;
                out[(size_t)(b0 + bl) * OUT_FEAT + o] = acc[m][n][i];
            }
        }
    }
}

extern "C" void kernel_launch(void* const* d_in, const int* in_sizes, int n_in,
                              void* d_out, int out_size, void* d_ws, size_t ws_size,
                              hipStream_t stream) {
    const float* x        = (const float*)d_in[0];
    const int*   uidx     = (const int*)d_in[1];
    const int*   iidx     = (const int*)d_in[2];
    const float* W_base   = (const float*)d_in[3];
    const float* b_base   = (const float*)d_in[4];
    const float* A        = (const float*)d_in[5];
    const float* B_user   = (const float*)d_in[6];
    const float* B_item   = (const float*)d_in[7];
    const float* W_common = (const float*)d_in[8];
    float* out = (float*)d_out;

    // workspace layout
    float*  a_buf = (float*)d_ws;                                     // 256 KB
    __bf16* x_bf  = (__bf16*)((char*)d_ws + (256 << 10));             // 8 MB
    __bf16* w_bf  = (__bf16*)((char*)d_ws + (256 << 10) + (8 << 20)); // 2 MB

    prep_kernel<<<BATCH, 256, 0, stream>>>(x, A, W_base, a_buf, x_bf, w_bf);

    dim3 grid(OUT_FEAT / BN, BATCH / BM);
    fused_kernel<<<grid, 256, 0, stream>>>(x_bf, w_bf, a_buf, uidx, iidx,
                                           b_base, B_user, B_item, W_common, out);
}